// Round 1
// baseline (498.160 us; speedup 1.0000x reference)
//
#include <hip/hip_runtime.h>

// Problem constants (fixed by the reference setup):
//   B=4, FREQ=256, TIME=512, E=512, all float32.
//   out[b, f*TIME+t, e] = x[b, f*TIME+t, e] + pe_1d[f, e] + pe_1d[t, e]
constexpr int B_    = 4;
constexpr int FREQ_ = 256;
constexpr int TIME_ = 512;
constexpr int E_    = 512;
constexpr int E4    = E_ / 4;               // 128 float4 per row
constexpr int N4    = FREQ_ * TIME_ * E4;   // float4 elements per batch = 16,777,216

__global__ void __launch_bounds__(256)
pe2d_add_kernel(const float4* __restrict__ x,
                const float4* __restrict__ pe,   // pe_1d as float4, rows of E4
                float4* __restrict__ out)
{
    const int stride = gridDim.x * blockDim.x;
    for (int i = blockIdx.x * blockDim.x + threadIdx.x; i < N4; i += stride) {
        // decompose i -> (f, t, e4); all powers of two -> shifts/masks
        const int e4  = i & (E4 - 1);        // i % 128
        const int row = i >> 7;              // i / 128
        const int t   = row & (TIME_ - 1);   // row % 512
        const int f   = row >> 9;            // row / 512  (< 256)

        const float4 pf = pe[f * E4 + e4];
        const float4 pt = pe[t * E4 + e4];
        float4 ps;
        ps.x = pf.x + pt.x;
        ps.y = pf.y + pt.y;
        ps.z = pf.z + pt.z;
        ps.w = pf.w + pt.w;

        // reuse the pe sum across all 4 batches (saves pe loads + index math)
        #pragma unroll
        for (int b = 0; b < B_; ++b) {
            const size_t idx = (size_t)b * N4 + i;
            float4 v = x[idx];
            v.x += ps.x;
            v.y += ps.y;
            v.z += ps.z;
            v.w += ps.w;
            out[idx] = v;
        }
    }
}

extern "C" void kernel_launch(void* const* d_in, const int* in_sizes, int n_in,
                              void* d_out, int out_size, void* d_ws, size_t ws_size,
                              hipStream_t stream)
{
    const float4* x  = (const float4*)d_in[0];   // (B, FREQ*TIME, E) fp32
    const float4* pe = (const float4*)d_in[1];   // (max(F,T)=512, E) fp32
    float4* out = (float4*)d_out;

    const int block = 256;
    const int grid  = 4096;   // grid-stride; ~16 iters/thread
    pe2d_add_kernel<<<grid, block, 0, stream>>>(x, pe, out);
}